// Round 5
// baseline (437.383 us; speedup 1.0000x reference)
//
#include <hip/hip_runtime.h>
#include <hip/hip_bf16.h>

typedef __attribute__((ext_vector_type(8))) short bf16x8;
typedef __attribute__((ext_vector_type(4))) float f32x4;

#define GLOBAL_AS __attribute__((address_space(1)))
#define LDS_AS __attribute__((address_space(3)))

#define DCH 1024
#define SEQ 4096
#define NBATCH 8

// RNE float -> bf16 (finite inputs)
static __device__ __forceinline__ unsigned int f2bf(float f) {
    unsigned int u = __float_as_uint(f);
    return (u + 0x7fffu + ((u >> 16) & 1u)) >> 16;
}

static __device__ __forceinline__ void async_copy16(const void* g, void* l) {
    __builtin_amdgcn_global_load_lds((const GLOBAL_AS void*)g, (LDS_AS void*)l, 16, 0, 0);
}

static __device__ __forceinline__ float gelu_tanh(float u) {
    float inner = 0.7978845608028654f * (u + 0.044715f * u * u * u);
    return 0.5f * u * (1.f + tanhf(inner));  // gelu approximate=True
}

// ---------------- fused prep: x fp32->bf16 (blocks 0..16383) +
// transpose/convert Wk/Wv -> bf16 W^T[h][k] (blocks 16384..18431) -------------
__global__ __launch_bounds__(256) void prep_kernel(
    const float4* __restrict__ x, uint4* __restrict__ xb,
    const float* __restrict__ Wk, const float* __restrict__ Wv,
    unsigned short* __restrict__ WkT, unsigned short* __restrict__ WvT)
{
    __shared__ float tile[32][33];
    int tid = threadIdx.x;
    if (blockIdx.x < 16384) {
        size_t t = (size_t)blockIdx.x * 256 + tid;  // 4M threads, 8 floats each
        float4 f0 = x[t * 2], f1 = x[t * 2 + 1];
        uint4 a;
        a.x = f2bf(f0.x) | (f2bf(f0.y) << 16);
        a.y = f2bf(f0.z) | (f2bf(f0.w) << 16);
        a.z = f2bf(f1.x) | (f2bf(f1.y) << 16);
        a.w = f2bf(f1.z) | (f2bf(f1.w) << 16);
        xb[t] = a;
    } else {
        int b2 = blockIdx.x - 16384;  // 2048 blocks: 32 h-tiles x 32 k-tiles x 2
        const float* src = (b2 >> 10) ? Wv : Wk;
        unsigned short* dst = (b2 >> 10) ? WvT : WkT;
        int h0 = (b2 & 31) * 32, k0 = ((b2 >> 5) & 31) * 32;
        int tx = tid & 31, ty = tid >> 5;  // 32 x 8
#pragma unroll
        for (int i = 0; i < 4; i++)
            tile[ty + i * 8][tx] = src[(size_t)(k0 + ty + i * 8) * DCH + h0 + tx];
        __syncthreads();
#pragma unroll
        for (int i = 0; i < 4; i++)
            dst[(size_t)(h0 + ty + i * 8) * DCH + k0 + tx] =
                (unsigned short)f2bf(tile[tx][ty + i * 8]);
    }
}

// ---------------- standalone wt (slow path only) -----------------------------
__global__ __launch_bounds__(256) void wt_kernel(
    const float* __restrict__ Wk, const float* __restrict__ Wv,
    unsigned short* __restrict__ WkT, unsigned short* __restrict__ WvT)
{
    __shared__ float tile[32][33];
    const float* src = blockIdx.z ? Wv : Wk;
    unsigned short* dst = blockIdx.z ? WvT : WkT;
    int h0 = blockIdx.x * 32, k0 = blockIdx.y * 32;
    int tx = threadIdx.x, ty = threadIdx.y;
#pragma unroll
    for (int i = 0; i < 4; i++)
        tile[ty + i * 8][tx] = src[(size_t)(k0 + ty + i * 8) * DCH + h0 + tx];
    __syncthreads();
#pragma unroll
    for (int i = 0; i < 4; i++)
        dst[(size_t)(h0 + ty + i * 8) * DCH + k0 + tx] =
            (unsigned short)f2bf(tile[tx][ty + i * 8]);
}

// ---------------- fast path: fused K/V projection + fmap + reduction ---------
// v4: 3-buffer counted-vmcnt pipeline (catalog T3+T4). Tile 256s x 128h,
// 512 threads = 8 waves (2 s-groups x 4 h-groups), BK=32, 32 K-iters.
// Per iter: stage tile t+2 (4 gload_lds/thread), ds_read 12 frags from
// buf[t%3], 32 MFMA (setprio-wrapped), then s_waitcnt vmcnt(4) -- t+1's
// loads landed, t+2's stay IN FLIGHT across the raw s_barrier (never
// drain to 0 in the main loop; that drain was v2's 43%-util ceiling and
// v3's regression). LDS 96 KB = 3 x (A 16K + K 8K + V 8K); 1 block/CU,
// hiding is intra-block (HK model). Per-wave 128s x 32h: mt=8 raises
// FLOP per LDS byte 32 -> 43 vs v2.
__global__ __launch_bounds__(512, 2) void kv_gemm_fast(
    const unsigned short* __restrict__ xb,
    const unsigned short* __restrict__ WkT,
    const unsigned short* __restrict__ WvT,
    const float* __restrict__ bk,
    const float* __restrict__ bv,
    float* __restrict__ part)
{
    __shared__ __align__(16) unsigned short sA[3][256 * 32];  // 48 KB
    __shared__ __align__(16) unsigned short sK[3][128 * 32];  // 24 KB
    __shared__ __align__(16) unsigned short sV[3][128 * 32];  // 24 KB

    // XCD swizzle: 1024 blocks = 8 XCD x 128; all 8 h-tiles of one
    // (n,s_tile) stay on the same XCD so the 512 KB A-panel L2-hits.
    int b = blockIdx.x;
    int r = b & 7, j = b >> 3;
    int h_tile = j & 7;                 // 8 h-tiles x 128h
    int ns = r * 16 + (j >> 3);         // 128 (n,s) pairs
    int n = ns >> 4, s_tile = ns & 15;
    int s0 = s_tile * 256, h0 = h_tile * 128;

    int tid = threadIdx.x;
    int lane = tid & 63, wid = tid >> 6;   // 8 waves
    int sg = wid >> 2, hg = wid & 3;       // 2 s-groups x 4 h-groups
    int col = lane & 15, lhi = lane >> 4;

    // A staging: 1024 chunks/tile, 2 per thread: c = i*512 + tid
    const unsigned short* gA[2];
#pragma unroll
    for (int i = 0; i < 2; i++) {
        int c = i * 512 + tid;
        int row = c >> 2, c8 = (c & 3) ^ (row & 3);
        gA[i] = xb + (size_t)(n * SEQ + s0 + row) * DCH + c8 * 8;
    }
    // K/V staging: 512 chunks each, 1 per thread: c = tid
    const unsigned short* gK;
    const unsigned short* gV;
    {
        int c = tid;
        int row = c >> 2, c8 = (c & 3) ^ (row & 3);
        gK = WkT + (size_t)(h0 + row) * DCH + c8 * 8;
        gV = WvT + (size_t)(h0 + row) * DCH + c8 * 8;
    }
    int aBase = wid * 64 * 8;  // LDS short-offset of this wave's lane-0 chunk

    f32x4 acck[8][2], accv[8][2];
#pragma unroll
    for (int mt = 0; mt < 8; mt++)
#pragma unroll
        for (int nt = 0; nt < 2; nt++) {
            acck[mt][nt] = (f32x4){0.f, 0.f, 0.f, 0.f};
            accv[mt][nt] = (f32x4){0.f, 0.f, 0.f, 0.f};
        }

    // prologue: stage tiles 0 and 1 (8 loads/thread), wait tile0 only
#pragma unroll
    for (int t0 = 0; t0 < 2; t0++) {
        int k0 = t0 * 32;
#pragma unroll
        for (int i = 0; i < 2; i++)
            async_copy16(gA[i] + k0, &sA[t0][i * 512 * 8 + aBase]);
        async_copy16(gK + k0, &sK[t0][aBase]);
        async_copy16(gV + k0, &sV[t0][aBase]);
    }
    asm volatile("s_waitcnt vmcnt(4)" ::: "memory");
    __builtin_amdgcn_sched_barrier(0);
    __builtin_amdgcn_s_barrier();
    __builtin_amdgcn_sched_barrier(0);

    int q = 0;  // buffer holding tile t
    for (int t = 0; t < 32; t++) {
        int w = q + 2 >= 3 ? q - 1 : q + 2;  // buffer for tile t+2
        if (t < 30) {
            int k0 = (t + 2) * 32;
#pragma unroll
            for (int i = 0; i < 2; i++)
                async_copy16(gA[i] + k0, &sA[w][i * 512 * 8 + aBase]);
            async_copy16(gK + k0, &sK[w][aBase]);
            async_copy16(gV + k0, &sV[w][aBase]);
        }
        // fragment reads from buf q (compiler inserts lgkmcnt before MFMA)
        bf16x8 af[8], bkf[2], bvf[2];
#pragma unroll
        for (int mt = 0; mt < 8; mt++) {
            int rowa = sg * 128 + mt * 16 + col;
            af[mt] = *((const bf16x8*)&sA[q][rowa * 32 + ((lhi ^ (rowa & 3)) * 8)]);
        }
#pragma unroll
        for (int nt = 0; nt < 2; nt++) {
            int rowb = hg * 32 + nt * 16 + col;
            int o = rowb * 32 + ((lhi ^ (rowb & 3)) * 8);
            bkf[nt] = *((const bf16x8*)&sK[q][o]);
            bvf[nt] = *((const bf16x8*)&sV[q][o]);
        }
        __builtin_amdgcn_s_setprio(1);
#pragma unroll
        for (int mt = 0; mt < 8; mt++)
#pragma unroll
            for (int nt = 0; nt < 2; nt++) {
                acck[mt][nt] = __builtin_amdgcn_mfma_f32_16x16x32_bf16(
                    af[mt], bkf[nt], acck[mt][nt], 0, 0, 0);
                accv[mt][nt] = __builtin_amdgcn_mfma_f32_16x16x32_bf16(
                    af[mt], bvf[nt], accv[mt][nt], 0, 0, 0);
            }
        __builtin_amdgcn_s_setprio(0);

        if (t < 30) {
            // t+1's 4 loads retired; t+2's 4 stay in flight across the barrier
            asm volatile("s_waitcnt vmcnt(4)" ::: "memory");
            __builtin_amdgcn_sched_barrier(0);
            __builtin_amdgcn_s_barrier();
            __builtin_amdgcn_sched_barrier(0);
        } else if (t == 30) {
            asm volatile("s_waitcnt vmcnt(0)" ::: "memory");
            __builtin_amdgcn_sched_barrier(0);
            __builtin_amdgcn_s_barrier();
            __builtin_amdgcn_sched_barrier(0);
        }
        q = q + 1 >= 3 ? 0 : q + 1;
    }

    // epilogue scratch aliased onto sA[0] (iter-31 readers touch only buf 1)
    float* redf = (float*)&sA[0][0];  // layout [sg][128][2]

    // fmap, pairwise product, reduce over the 256 s-rows of this tile
#pragma unroll
    for (int nt = 0; nt < 2; nt++) {
        int h_local = hg * 32 + nt * 16 + col;
        float bkv = bk[h0 + h_local];
        float bvv = bv[h0 + h_local];
        float pkv = 0.f, pks = 0.f;
#pragma unroll
        for (int mt = 0; mt < 8; mt++)
#pragma unroll
            for (int rr = 0; rr < 4; rr++) {
                float ck = acck[mt][nt][rr] + bkv;
                float cv = accv[mt][nt][rr] + bvv;
                float kq = ck > 0.f ? ck + 1.f : __expf(ck);  // elu+1
                pkv += kq * cv;
                pks += kq;
            }
        pkv += __shfl_xor(pkv, 16);
        pkv += __shfl_xor(pkv, 32);
        pks += __shfl_xor(pks, 16);
        pks += __shfl_xor(pks, 32);
        if (lhi == 0) {
            redf[(sg * 128 + h_local) * 2 + 0] = pkv;
            redf[(sg * 128 + h_local) * 2 + 1] = pks;
        }
    }
    __syncthreads();
    if (tid < 256) {
        int h = tid & 127, t2 = tid >> 7;
        float v = redf[h * 2 + t2] + redf[(128 + h) * 2 + t2];
        int ht = h_tile * 2 + (h >> 6);
        part[(((size_t)(n * 16 + ht) * 2 + t2) * 16 + s_tile) * 64 + (h & 63)] = v;
    }
}

// ---------------- slow fallback (fp32 staging, no xb needed) -----------------
__global__ __launch_bounds__(512) void kv_gemm_slow(
    const float* __restrict__ x,
    const unsigned short* __restrict__ WkT,
    const unsigned short* __restrict__ WvT,
    const float* __restrict__ bk,
    const float* __restrict__ bv,
    float* __restrict__ part)
{
    __shared__ unsigned short sA[128 * 64];
    __shared__ unsigned short sK[128 * 64];
    __shared__ unsigned short sV[128 * 64];
    __shared__ float red[2][128][2];

    int b = blockIdx.x;
    int r = b & 7, j = b >> 3;
    int ns = r * 32 + (j >> 3);
    int h_tile = j & 7;
    int n = ns >> 5, s_tile = ns & 31;
    int s0 = s_tile * 128, h0 = h_tile * 128;

    const float* xA = x + ((size_t)(n * SEQ + s0)) * DCH;

    int tid = threadIdx.x;
    int lane = tid & 63, wid = tid >> 6;
    int wsg = wid >> 2, wh = wid & 3;
    int col = lane & 15, lhi = lane >> 4;

    f32x4 acck[4][2], accv[4][2];
#pragma unroll
    for (int mt = 0; mt < 4; mt++)
#pragma unroll
        for (int nt = 0; nt < 2; nt++) {
            acck[mt][nt] = (f32x4){0.f, 0.f, 0.f, 0.f};
            accv[mt][nt] = (f32x4){0.f, 0.f, 0.f, 0.f};
        }

    for (int kk = 0; kk < 16; kk++) {
        int k0 = kk * 64;
#pragma unroll
        for (int i = 0; i < 2; i++) {
            int c = tid + i * 512;
            int row = c >> 3, c8 = c & 7;
            const float4* p = (const float4*)(xA + (size_t)row * DCH + k0 + c8 * 8);
            float4 f0 = p[0], f1 = p[1];
            unsigned int p0 = f2bf(f0.x) | (f2bf(f0.y) << 16);
            unsigned int p1 = f2bf(f0.z) | (f2bf(f0.w) << 16);
            unsigned int p2 = f2bf(f1.x) | (f2bf(f1.y) << 16);
            unsigned int p3 = f2bf(f1.z) | (f2bf(f1.w) << 16);
            uint4 pk = {p0, p1, p2, p3};
            int g = c8 ^ (row & 7);
            *((uint4*)&sA[row * 64 + g * 8]) = pk;
        }
#pragma unroll
        for (int i = 0; i < 2; i++) {
            int c = tid + i * 512;
            int row = c >> 3, c8 = c & 7;
            int g = c8 ^ (row & 7);
            *((uint4*)&sK[row * 64 + g * 8]) =
                *((const uint4*)(WkT + (size_t)(h0 + row) * DCH + k0 + c8 * 8));
            *((uint4*)&sV[row * 64 + g * 8]) =
                *((const uint4*)(WvT + (size_t)(h0 + row) * DCH + k0 + c8 * 8));
        }
        __syncthreads();
#pragma unroll
        for (int ks = 0; ks < 2; ks++) {
            bf16x8 af[4], bkf[2], bvf[2];
            int gg = ks * 4 + lhi;
#pragma unroll
            for (int mt = 0; mt < 4; mt++) {
                int rowa = wsg * 64 + mt * 16 + col;
                af[mt] = *((const bf16x8*)&sA[rowa * 64 + ((gg ^ (rowa & 7)) * 8)]);
            }
#pragma unroll
            for (int nt = 0; nt < 2; nt++) {
                int rowb = wh * 32 + nt * 16 + col;
                int o = rowb * 64 + ((gg ^ (rowb & 7)) * 8);
                bkf[nt] = *((const bf16x8*)&sK[o]);
                bvf[nt] = *((const bf16x8*)&sV[o]);
            }
#pragma unroll
            for (int mt = 0; mt < 4; mt++)
#pragma unroll
                for (int nt = 0; nt < 2; nt++) {
                    acck[mt][nt] = __builtin_amdgcn_mfma_f32_16x16x32_bf16(
                        af[mt], bkf[nt], acck[mt][nt], 0, 0, 0);
                    accv[mt][nt] = __builtin_amdgcn_mfma_f32_16x16x32_bf16(
                        af[mt], bvf[nt], accv[mt][nt], 0, 0, 0);
                }
        }
        __syncthreads();
    }

#pragma unroll
    for (int nt = 0; nt < 2; nt++) {
        int h_local = wh * 32 + nt * 16 + col;
        float bkv = bk[h0 + h_local];
        float bvv = bv[h0 + h_local];
        float pkv = 0.f, pks = 0.f;
#pragma unroll
        for (int mt = 0; mt < 4; mt++)
#pragma unroll
            for (int rr = 0; rr < 4; rr++) {
                float ck = acck[mt][nt][rr] + bkv;
                float cv = accv[mt][nt][rr] + bvv;
                float kq = ck > 0.f ? ck + 1.f : __expf(ck);
                pkv += kq * cv;
                pks += kq;
            }
        pkv += __shfl_xor(pkv, 16);
        pkv += __shfl_xor(pkv, 32);
        pks += __shfl_xor(pks, 16);
        pks += __shfl_xor(pks, 32);
        if (lhi == 0) {
            red[wsg][h_local][0] = pkv;
            red[wsg][h_local][1] = pks;
        }
    }
    __syncthreads();
    if (tid < 256) {
        int h = tid & 127, t = tid >> 7;
        float v = red[0][h][t] + red[1][h][t];
        int ht = h_tile * 2 + (h >> 6);
        part[(((size_t)(n * 16 + ht) * 2 + t) * 32 + s_tile) * 64 + (h & 63)] = v;
    }
}

// -------- reduce partials -> V = KV/Ksum, then k-split GEMM vs Wo ------------
// nst = number of s-tiles in the part layout (16 fast path, 32 slow path)
__global__ __launch_bounds__(256) void out_part_kernel(
    const float* __restrict__ part, const float* __restrict__ Wo,
    float* __restrict__ part2, int nst)
{
    __shared__ float skv[128], sks[128], vs[128];
    int n = blockIdx.x, kc = blockIdx.y, ob = blockIdx.z;
    int tid = threadIdx.x;
    {
        int h = tid & 127, t = tid >> 7;
        int ht = kc * 2 + (h >> 6);
        const float* base = part + (((size_t)(n * 16 + ht) * 2 + t) * nst) * 64;
        float s = 0.f;
#pragma unroll 4
        for (int st = 0; st < nst; st++) s += base[st * 64 + (h & 63)];
        if (t == 0) skv[h] = s; else sks[h] = s;
    }
    __syncthreads();
    if (tid < 128) vs[tid] = skv[tid] / sks[tid];
    __syncthreads();
    int o = ob * 256 + tid;
    float acc = 0.f;
#pragma unroll 8
    for (int k = 0; k < 128; k++)
        acc += vs[k] * Wo[(size_t)(kc * 128 + k) * DCH + o];
    part2[(size_t)(n * 8 + kc) * DCH + o] = acc;
}

// ---------------- finish (k-split sum + bias + gelu) fused with broadcast ----
__global__ __launch_bounds__(256) void bcast_kernel(
    const float4* __restrict__ part2, const float4* __restrict__ bo,
    float4* __restrict__ out)
{
    int n = blockIdx.x >> 7;
    int sc = blockIdx.x & 127;
    int tid = threadIdx.x;  // one float4 column group
    float4 a = bo[tid];
#pragma unroll
    for (int kc = 0; kc < 8; kc++) {
        float4 p = part2[(size_t)(n * 8 + kc) * 256 + tid];
        a.x += p.x; a.y += p.y; a.z += p.z; a.w += p.w;
    }
    float4 v;
    v.x = gelu_tanh(a.x);
    v.y = gelu_tanh(a.y);
    v.z = gelu_tanh(a.z);
    v.w = gelu_tanh(a.w);
    size_t base = ((size_t)(n * SEQ) + (size_t)sc * 32) * 256 + tid;
#pragma unroll 4
    for (int s = 0; s < 32; s++)
        out[base + (size_t)s * 256] = v;
}

extern "C" void kernel_launch(void* const* d_in, const int* in_sizes, int n_in,
                              void* d_out, int out_size, void* d_ws, size_t ws_size,
                              hipStream_t stream) {
    const float* x  = (const float*)d_in[0];
    // Wq (d_in[1]) / bq (d_in[2]) cancel: Q>0 in V = Q*KV/(Q*Ksum + 1e-6)
    // up to <=5e-8 relative perturbation (validated: absmax 2.4e-4).
    const float* Wk = (const float*)d_in[3];
    const float* bk = (const float*)d_in[4];
    const float* Wv = (const float*)d_in[5];
    const float* bv = (const float*)d_in[6];
    const float* Wo = (const float*)d_in[7];
    const float* bo = (const float*)d_in[8];

    const size_t XB_BYTES = (size_t)NBATCH * SEQ * DCH * 2;       // 64 MB
    // tail: WkT(2M) + WvT(2M) + part(8M) + part2(512K)
    const size_t TAIL = (4u << 20) + (8u << 20) + (1u << 19);
    bool fast = ws_size >= XB_BYTES + TAIL;

    char* ws = (char*)d_ws;
    unsigned short* xb = (unsigned short*)ws;                  // fast path only
    char* base = fast ? ws + XB_BYTES : ws;
    unsigned short* WkT = (unsigned short*)base;               // 2 MB bf16 [h][k]
    unsigned short* WvT = WkT + 1024 * 1024;                   // 2 MB
    float* part  = (float*)(base + 4 * 1024 * 1024);           // 8 MB partials
    float* part2 = part + (size_t)8 * 16 * 2 * 32 * 64;        // 512 KB

    if (fast) {
        prep_kernel<<<18432, 256, 0, stream>>>((const float4*)x, (uint4*)xb,
                                               Wk, Wv, WkT, WvT);
        kv_gemm_fast<<<1024, 512, 0, stream>>>(xb, WkT, WvT, bk, bv, part);
        out_part_kernel<<<dim3(8, 8, 4), 256, 0, stream>>>(part, Wo, part2, 16);
    } else {
        wt_kernel<<<dim3(32, 32, 2), dim3(32, 8), 0, stream>>>(Wk, Wv, WkT, WvT);
        kv_gemm_slow<<<2048, 512, 0, stream>>>(x, WkT, WvT, bk, bv, part);
        out_part_kernel<<<dim3(8, 8, 4), 256, 0, stream>>>(part, Wo, part2, 32);
    }
    bcast_kernel<<<1024, 256, 0, stream>>>((const float4*)part2, (const float4*)bo,
                                           (float4*)d_out);
}

// Round 6
// 430.907 us; speedup vs baseline: 1.0150x; 1.0150x over previous
//
#include <hip/hip_runtime.h>
#include <hip/hip_bf16.h>

typedef __attribute__((ext_vector_type(8))) short bf16x8;
typedef __attribute__((ext_vector_type(4))) float f32x4;

#define GLOBAL_AS __attribute__((address_space(1)))
#define LDS_AS __attribute__((address_space(3)))

#define DCH 1024
#define SEQ 4096
#define NBATCH 8

// RNE float -> bf16 (finite inputs)
static __device__ __forceinline__ unsigned int f2bf(float f) {
    unsigned int u = __float_as_uint(f);
    return (u + 0x7fffu + ((u >> 16) & 1u)) >> 16;
}

static __device__ __forceinline__ void async_copy16(const void* g, void* l) {
    __builtin_amdgcn_global_load_lds((const GLOBAL_AS void*)g, (LDS_AS void*)l, 16, 0, 0);
}

static __device__ __forceinline__ float gelu_tanh(float u) {
    float inner = 0.7978845608028654f * (u + 0.044715f * u * u * u);
    return 0.5f * u * (1.f + tanhf(inner));  // gelu approximate=True
}

// ---------------- fused prep: x fp32->bf16 (blocks 0..16383) +
// transpose/convert Wk/Wv -> bf16 W^T[h][k] (blocks 16384..18431) -------------
__global__ __launch_bounds__(256) void prep_kernel(
    const float4* __restrict__ x, uint4* __restrict__ xb,
    const float* __restrict__ Wk, const float* __restrict__ Wv,
    unsigned short* __restrict__ WkT, unsigned short* __restrict__ WvT)
{
    __shared__ float tile[32][33];
    int tid = threadIdx.x;
    if (blockIdx.x < 16384) {
        size_t t = (size_t)blockIdx.x * 256 + tid;  // 4M threads, 8 floats each
        float4 f0 = x[t * 2], f1 = x[t * 2 + 1];
        uint4 a;
        a.x = f2bf(f0.x) | (f2bf(f0.y) << 16);
        a.y = f2bf(f0.z) | (f2bf(f0.w) << 16);
        a.z = f2bf(f1.x) | (f2bf(f1.y) << 16);
        a.w = f2bf(f1.z) | (f2bf(f1.w) << 16);
        xb[t] = a;
    } else {
        int b2 = blockIdx.x - 16384;  // 2048 blocks: 32 h-tiles x 32 k-tiles x 2
        const float* src = (b2 >> 10) ? Wv : Wk;
        unsigned short* dst = (b2 >> 10) ? WvT : WkT;
        int h0 = (b2 & 31) * 32, k0 = ((b2 >> 5) & 31) * 32;
        int tx = tid & 31, ty = tid >> 5;  // 32 x 8
#pragma unroll
        for (int i = 0; i < 4; i++)
            tile[ty + i * 8][tx] = src[(size_t)(k0 + ty + i * 8) * DCH + h0 + tx];
        __syncthreads();
#pragma unroll
        for (int i = 0; i < 4; i++)
            dst[(size_t)(h0 + ty + i * 8) * DCH + k0 + tx] =
                (unsigned short)f2bf(tile[tx][ty + i * 8]);
    }
}

// ---------------- standalone wt (slow path only) -----------------------------
__global__ __launch_bounds__(256) void wt_kernel(
    const float* __restrict__ Wk, const float* __restrict__ Wv,
    unsigned short* __restrict__ WkT, unsigned short* __restrict__ WvT)
{
    __shared__ float tile[32][33];
    const float* src = blockIdx.z ? Wv : Wk;
    unsigned short* dst = blockIdx.z ? WvT : WkT;
    int h0 = blockIdx.x * 32, k0 = blockIdx.y * 32;
    int tx = threadIdx.x, ty = threadIdx.y;
#pragma unroll
    for (int i = 0; i < 4; i++)
        tile[ty + i * 8][tx] = src[(size_t)(k0 + ty + i * 8) * DCH + h0 + tx];
    __syncthreads();
#pragma unroll
    for (int i = 0; i < 4; i++)
        dst[(size_t)(h0 + ty + i * 8) * DCH + k0 + tx] =
            (unsigned short)f2bf(tile[tx][ty + i * 8]);
}

// ---------------- fast path: fused K/V projection + fmap + reduction ---------
// v5 = v4 with the BANK-CONFLICT FIX. v4 measured 181us with
// SQ_LDS_BANK_CONFLICT=12.6M: BK=32 rows are 64B (4 chunks), and the v2-style
// swizzle chunk^(row&3) has period 4 in row for the bank-quad index
// (row&1,(lhi^(row&3))) -> only 4 of 8 quads used -> 8 lanes/bank (~2.9x LDS,
// matches 435K cyc measured vs 144K conflict-free). Fix: swizzle with
// (row>>1)&3 -- quad (row&1, lhi^((row>>1)&3)) is bijective over every 8
// consecutive rows, same conflict-free structure as v2's 128B-row layout.
// Applied on BOTH the staging source column and the fragment read (rule #21).
// Everything else identical to v4 (3-buffer counted-vmcnt pipeline, never
// draining vmcnt to 0 in the main loop).
__global__ __launch_bounds__(512, 2) void kv_gemm_fast(
    const unsigned short* __restrict__ xb,
    const unsigned short* __restrict__ WkT,
    const unsigned short* __restrict__ WvT,
    const float* __restrict__ bk,
    const float* __restrict__ bv,
    float* __restrict__ part)
{
    __shared__ __align__(16) unsigned short sA[3][256 * 32];  // 48 KB
    __shared__ __align__(16) unsigned short sK[3][128 * 32];  // 24 KB
    __shared__ __align__(16) unsigned short sV[3][128 * 32];  // 24 KB

    // XCD swizzle: 1024 blocks = 8 XCD x 128; all 8 h-tiles of one
    // (n,s_tile) stay on the same XCD so the 512 KB A-panel L2-hits.
    int b = blockIdx.x;
    int r = b & 7, j = b >> 3;
    int h_tile = j & 7;                 // 8 h-tiles x 128h
    int ns = r * 16 + (j >> 3);         // 128 (n,s) pairs
    int n = ns >> 4, s_tile = ns & 15;
    int s0 = s_tile * 256, h0 = h_tile * 128;

    int tid = threadIdx.x;
    int lane = tid & 63, wid = tid >> 6;   // 8 waves
    int sg = wid >> 2, hg = wid & 3;       // 2 s-groups x 4 h-groups
    int col = lane & 15, lhi = lane >> 4;

    // A staging: 1024 chunks/tile, 2 per thread: c = i*512 + tid
    const unsigned short* gA[2];
#pragma unroll
    for (int i = 0; i < 2; i++) {
        int c = i * 512 + tid;
        int row = c >> 2, c8 = (c & 3) ^ ((row >> 1) & 3);
        gA[i] = xb + (size_t)(n * SEQ + s0 + row) * DCH + c8 * 8;
    }
    // K/V staging: 512 chunks each, 1 per thread: c = tid
    const unsigned short* gK;
    const unsigned short* gV;
    {
        int c = tid;
        int row = c >> 2, c8 = (c & 3) ^ ((row >> 1) & 3);
        gK = WkT + (size_t)(h0 + row) * DCH + c8 * 8;
        gV = WvT + (size_t)(h0 + row) * DCH + c8 * 8;
    }
    int aBase = wid * 64 * 8;  // LDS short-offset of this wave's lane-0 chunk

    f32x4 acck[8][2], accv[8][2];
#pragma unroll
    for (int mt = 0; mt < 8; mt++)
#pragma unroll
        for (int nt = 0; nt < 2; nt++) {
            acck[mt][nt] = (f32x4){0.f, 0.f, 0.f, 0.f};
            accv[mt][nt] = (f32x4){0.f, 0.f, 0.f, 0.f};
        }

    // prologue: stage tiles 0 and 1 (8 loads/thread), wait tile0 only
#pragma unroll
    for (int t0 = 0; t0 < 2; t0++) {
        int k0 = t0 * 32;
#pragma unroll
        for (int i = 0; i < 2; i++)
            async_copy16(gA[i] + k0, &sA[t0][i * 512 * 8 + aBase]);
        async_copy16(gK + k0, &sK[t0][aBase]);
        async_copy16(gV + k0, &sV[t0][aBase]);
    }
    asm volatile("s_waitcnt vmcnt(4)" ::: "memory");
    __builtin_amdgcn_sched_barrier(0);
    __builtin_amdgcn_s_barrier();
    __builtin_amdgcn_sched_barrier(0);

    int q = 0;  // buffer holding tile t
    for (int t = 0; t < 32; t++) {
        int w = q + 2 >= 3 ? q - 1 : q + 2;  // buffer for tile t+2
        if (t < 30) {
            int k0 = (t + 2) * 32;
#pragma unroll
            for (int i = 0; i < 2; i++)
                async_copy16(gA[i] + k0, &sA[w][i * 512 * 8 + aBase]);
            async_copy16(gK + k0, &sK[w][aBase]);
            async_copy16(gV + k0, &sV[w][aBase]);
        }
        // fragment reads from buf q (compiler inserts lgkmcnt before MFMA)
        bf16x8 af[8], bkf[2], bvf[2];
#pragma unroll
        for (int mt = 0; mt < 8; mt++) {
            int rowa = sg * 128 + mt * 16 + col;
            af[mt] = *((const bf16x8*)&sA[q][rowa * 32 + ((lhi ^ ((rowa >> 1) & 3)) * 8)]);
        }
#pragma unroll
        for (int nt = 0; nt < 2; nt++) {
            int rowb = hg * 32 + nt * 16 + col;
            int o = rowb * 32 + ((lhi ^ ((rowb >> 1) & 3)) * 8);
            bkf[nt] = *((const bf16x8*)&sK[q][o]);
            bvf[nt] = *((const bf16x8*)&sV[q][o]);
        }
        __builtin_amdgcn_s_setprio(1);
#pragma unroll
        for (int mt = 0; mt < 8; mt++)
#pragma unroll
            for (int nt = 0; nt < 2; nt++) {
                acck[mt][nt] = __builtin_amdgcn_mfma_f32_16x16x32_bf16(
                    af[mt], bkf[nt], acck[mt][nt], 0, 0, 0);
                accv[mt][nt] = __builtin_amdgcn_mfma_f32_16x16x32_bf16(
                    af[mt], bvf[nt], accv[mt][nt], 0, 0, 0);
            }
        __builtin_amdgcn_s_setprio(0);

        if (t < 30) {
            // t+1's 4 loads retired; t+2's 4 stay in flight across the barrier
            asm volatile("s_waitcnt vmcnt(4)" ::: "memory");
            __builtin_amdgcn_sched_barrier(0);
            __builtin_amdgcn_s_barrier();
            __builtin_amdgcn_sched_barrier(0);
        } else if (t == 30) {
            asm volatile("s_waitcnt vmcnt(0)" ::: "memory");
            __builtin_amdgcn_sched_barrier(0);
            __builtin_amdgcn_s_barrier();
            __builtin_amdgcn_sched_barrier(0);
        }
        q = q + 1 >= 3 ? 0 : q + 1;
    }

    // epilogue scratch aliased onto sA[0] (iter-31 readers touch only buf 1)
    float* redf = (float*)&sA[0][0];  // layout [sg][128][2]

    // fmap, pairwise product, reduce over the 256 s-rows of this tile
#pragma unroll
    for (int nt = 0; nt < 2; nt++) {
        int h_local = hg * 32 + nt * 16 + col;
        float bkv = bk[h0 + h_local];
        float bvv = bv[h0 + h_local];
        float pkv = 0.f, pks = 0.f;
#pragma unroll
        for (int mt = 0; mt < 8; mt++)
#pragma unroll
            for (int rr = 0; rr < 4; rr++) {
                float ck = acck[mt][nt][rr] + bkv;
                float cv = accv[mt][nt][rr] + bvv;
                float kq = ck > 0.f ? ck + 1.f : __expf(ck);  // elu+1
                pkv += kq * cv;
                pks += kq;
            }
        pkv += __shfl_xor(pkv, 16);
        pkv += __shfl_xor(pkv, 32);
        pks += __shfl_xor(pks, 16);
        pks += __shfl_xor(pks, 32);
        if (lhi == 0) {
            redf[(sg * 128 + h_local) * 2 + 0] = pkv;
            redf[(sg * 128 + h_local) * 2 + 1] = pks;
        }
    }
    __syncthreads();
    if (tid < 256) {
        int h = tid & 127, t2 = tid >> 7;
        float v = redf[h * 2 + t2] + redf[(128 + h) * 2 + t2];
        int ht = h_tile * 2 + (h >> 6);
        part[(((size_t)(n * 16 + ht) * 2 + t2) * 16 + s_tile) * 64 + (h & 63)] = v;
    }
}

// ---------------- slow fallback (fp32 staging, no xb needed) -----------------
__global__ __launch_bounds__(512) void kv_gemm_slow(
    const float* __restrict__ x,
    const unsigned short* __restrict__ WkT,
    const unsigned short* __restrict__ WvT,
    const float* __restrict__ bk,
    const float* __restrict__ bv,
    float* __restrict__ part)
{
    __shared__ unsigned short sA[128 * 64];
    __shared__ unsigned short sK[128 * 64];
    __shared__ unsigned short sV[128 * 64];
    __shared__ float red[2][128][2];

    int b = blockIdx.x;
    int r = b & 7, j = b >> 3;
    int ns = r * 32 + (j >> 3);
    int h_tile = j & 7;
    int n = ns >> 5, s_tile = ns & 31;
    int s0 = s_tile * 128, h0 = h_tile * 128;

    const float* xA = x + ((size_t)(n * SEQ + s0)) * DCH;

    int tid = threadIdx.x;
    int lane = tid & 63, wid = tid >> 6;
    int wsg = wid >> 2, wh = wid & 3;
    int col = lane & 15, lhi = lane >> 4;

    f32x4 acck[4][2], accv[4][2];
#pragma unroll
    for (int mt = 0; mt < 4; mt++)
#pragma unroll
        for (int nt = 0; nt < 2; nt++) {
            acck[mt][nt] = (f32x4){0.f, 0.f, 0.f, 0.f};
            accv[mt][nt] = (f32x4){0.f, 0.f, 0.f, 0.f};
        }

    for (int kk = 0; kk < 16; kk++) {
        int k0 = kk * 64;
#pragma unroll
        for (int i = 0; i < 2; i++) {
            int c = tid + i * 512;
            int row = c >> 3, c8 = c & 7;
            const float4* p = (const float4*)(xA + (size_t)row * DCH + k0 + c8 * 8);
            float4 f0 = p[0], f1 = p[1];
            unsigned int p0 = f2bf(f0.x) | (f2bf(f0.y) << 16);
            unsigned int p1 = f2bf(f0.z) | (f2bf(f0.w) << 16);
            unsigned int p2 = f2bf(f1.x) | (f2bf(f1.y) << 16);
            unsigned int p3 = f2bf(f1.z) | (f2bf(f1.w) << 16);
            uint4 pk = {p0, p1, p2, p3};
            int g = c8 ^ (row & 7);
            *((uint4*)&sA[row * 64 + g * 8]) = pk;
        }
#pragma unroll
        for (int i = 0; i < 2; i++) {
            int c = tid + i * 512;
            int row = c >> 3, c8 = c & 7;
            int g = c8 ^ (row & 7);
            *((uint4*)&sK[row * 64 + g * 8]) =
                *((const uint4*)(WkT + (size_t)(h0 + row) * DCH + k0 + c8 * 8));
            *((uint4*)&sV[row * 64 + g * 8]) =
                *((const uint4*)(WvT + (size_t)(h0 + row) * DCH + k0 + c8 * 8));
        }
        __syncthreads();
#pragma unroll
        for (int ks = 0; ks < 2; ks++) {
            bf16x8 af[4], bkf[2], bvf[2];
            int gg = ks * 4 + lhi;
#pragma unroll
            for (int mt = 0; mt < 4; mt++) {
                int rowa = wsg * 64 + mt * 16 + col;
                af[mt] = *((const bf16x8*)&sA[rowa * 64 + ((gg ^ (rowa & 7)) * 8)]);
            }
#pragma unroll
            for (int nt = 0; nt < 2; nt++) {
                int rowb = wh * 32 + nt * 16 + col;
                int o = rowb * 64 + ((gg ^ (rowb & 7)) * 8);
                bkf[nt] = *((const bf16x8*)&sK[o]);
                bvf[nt] = *((const bf16x8*)&sV[o]);
            }
#pragma unroll
            for (int mt = 0; mt < 4; mt++)
#pragma unroll
                for (int nt = 0; nt < 2; nt++) {
                    acck[mt][nt] = __builtin_amdgcn_mfma_f32_16x16x32_bf16(
                        af[mt], bkf[nt], acck[mt][nt], 0, 0, 0);
                    accv[mt][nt] = __builtin_amdgcn_mfma_f32_16x16x32_bf16(
                        af[mt], bvf[nt], accv[mt][nt], 0, 0, 0);
                }
        }
        __syncthreads();
    }

#pragma unroll
    for (int nt = 0; nt < 2; nt++) {
        int h_local = wh * 32 + nt * 16 + col;
        float bkv = bk[h0 + h_local];
        float bvv = bv[h0 + h_local];
        float pkv = 0.f, pks = 0.f;
#pragma unroll
        for (int mt = 0; mt < 4; mt++)
#pragma unroll
            for (int rr = 0; rr < 4; rr++) {
                float ck = acck[mt][nt][rr] + bkv;
                float cv = accv[mt][nt][rr] + bvv;
                float kq = ck > 0.f ? ck + 1.f : __expf(ck);
                pkv += kq * cv;
                pks += kq;
            }
        pkv += __shfl_xor(pkv, 16);
        pkv += __shfl_xor(pkv, 32);
        pks += __shfl_xor(pks, 16);
        pks += __shfl_xor(pks, 32);
        if (lhi == 0) {
            red[wsg][h_local][0] = pkv;
            red[wsg][h_local][1] = pks;
        }
    }
    __syncthreads();
    if (tid < 256) {
        int h = tid & 127, t = tid >> 7;
        float v = red[0][h][t] + red[1][h][t];
        int ht = h_tile * 2 + (h >> 6);
        part[(((size_t)(n * 16 + ht) * 2 + t) * 32 + s_tile) * 64 + (h & 63)] = v;
    }
}

// -------- reduce partials -> V = KV/Ksum, then k-split GEMM vs Wo ------------
// nst = number of s-tiles in the part layout (16 fast path, 32 slow path)
__global__ __launch_bounds__(256) void out_part_kernel(
    const float* __restrict__ part, const float* __restrict__ Wo,
    float* __restrict__ part2, int nst)
{
    __shared__ float skv[128], sks[128], vs[128];
    int n = blockIdx.x, kc = blockIdx.y, ob = blockIdx.z;
    int tid = threadIdx.x;
    {
        int h = tid & 127, t = tid >> 7;
        int ht = kc * 2 + (h >> 6);
        const float* base = part + (((size_t)(n * 16 + ht) * 2 + t) * nst) * 64;
        float s = 0.f;
#pragma unroll 4
        for (int st = 0; st < nst; st++) s += base[st * 64 + (h & 63)];
        if (t == 0) skv[h] = s; else sks[h] = s;
    }
    __syncthreads();
    if (tid < 128) vs[tid] = skv[tid] / sks[tid];
    __syncthreads();
    int o = ob * 256 + tid;
    float acc = 0.f;
#pragma unroll 8
    for (int k = 0; k < 128; k++)
        acc += vs[k] * Wo[(size_t)(kc * 128 + k) * DCH + o];
    part2[(size_t)(n * 8 + kc) * DCH + o] = acc;
}

// ---------------- finish (k-split sum + bias + gelu) fused with broadcast ----
__global__ __launch_bounds__(256) void bcast_kernel(
    const float4* __restrict__ part2, const float4* __restrict__ bo,
    float4* __restrict__ out)
{
    int n = blockIdx.x >> 7;
    int sc = blockIdx.x & 127;
    int tid = threadIdx.x;  // one float4 column group
    float4 a = bo[tid];
#pragma unroll
    for (int kc = 0; kc < 8; kc++) {
        float4 p = part2[(size_t)(n * 8 + kc) * 256 + tid];
        a.x += p.x; a.y += p.y; a.z += p.z; a.w += p.w;
    }
    float4 v;
    v.x = gelu_tanh(a.x);
    v.y = gelu_tanh(a.y);
    v.z = gelu_tanh(a.z);
    v.w = gelu_tanh(a.w);
    size_t base = ((size_t)(n * SEQ) + (size_t)sc * 32) * 256 + tid;
#pragma unroll 4
    for (int s = 0; s < 32; s++)
        out[base + (size_t)s * 256] = v;
}

extern "C" void kernel_launch(void* const* d_in, const int* in_sizes, int n_in,
                              void* d_out, int out_size, void* d_ws, size_t ws_size,
                              hipStream_t stream) {
    const float* x  = (const float*)d_in[0];
    // Wq (d_in[1]) / bq (d_in[2]) cancel: Q>0 in V = Q*KV/(Q*Ksum + 1e-6)
    // up to <=5e-8 relative perturbation (validated: absmax 2.4e-4).
    const float* Wk = (const float*)d_in[3];
    const float* bk = (const float*)d_in[4];
    const float* Wv = (const float*)d_in[5];
    const float* bv = (const float*)d_in[6];
    const float* Wo = (const float*)d_in[7];
    const float* bo = (const float*)d_in[8];

    const size_t XB_BYTES = (size_t)NBATCH * SEQ * DCH * 2;       // 64 MB
    // tail: WkT(2M) + WvT(2M) + part(8M) + part2(512K)
    const size_t TAIL = (4u << 20) + (8u << 20) + (1u << 19);
    bool fast = ws_size >= XB_BYTES + TAIL;

    char* ws = (char*)d_ws;
    unsigned short* xb = (unsigned short*)ws;                  // fast path only
    char* base = fast ? ws + XB_BYTES : ws;
    unsigned short* WkT = (unsigned short*)base;               // 2 MB bf16 [h][k]
    unsigned short* WvT = WkT + 1024 * 1024;                   // 2 MB
    float* part  = (float*)(base + 4 * 1024 * 1024);           // 8 MB partials
    float* part2 = part + (size_t)8 * 16 * 2 * 32 * 64;        // 512 KB

    if (fast) {
        prep_kernel<<<18432, 256, 0, stream>>>((const float4*)x, (uint4*)xb,
                                               Wk, Wv, WkT, WvT);
        kv_gemm_fast<<<1024, 512, 0, stream>>>(xb, WkT, WvT, bk, bv, part);
        out_part_kernel<<<dim3(8, 8, 4), 256, 0, stream>>>(part, Wo, part2, 16);
    } else {
        wt_kernel<<<dim3(32, 32, 2), dim3(32, 8), 0, stream>>>(Wk, Wv, WkT, WvT);
        kv_gemm_slow<<<2048, 512, 0, stream>>>(x, WkT, WvT, bk, bv, part);
        out_part_kernel<<<dim3(8, 8, 4), 256, 0, stream>>>(part, Wo, part2, 32);
    }
    bcast_kernel<<<1024, 256, 0, stream>>>((const float4*)part2, (const float4*)bo,
                                           (float4*)d_out);
}

// Round 7
// 426.908 us; speedup vs baseline: 1.0245x; 1.0094x over previous
//
#include <hip/hip_runtime.h>
#include <hip/hip_bf16.h>

typedef __attribute__((ext_vector_type(8))) short bf16x8;
typedef __attribute__((ext_vector_type(4))) float f32x4;

#define GLOBAL_AS __attribute__((address_space(1)))
#define LDS_AS __attribute__((address_space(3)))

#define DCH 1024
#define SEQ 4096
#define NBATCH 8

// RNE float -> bf16 (finite inputs)
static __device__ __forceinline__ unsigned int f2bf(float f) {
    unsigned int u = __float_as_uint(f);
    return (u + 0x7fffu + ((u >> 16) & 1u)) >> 16;
}

static __device__ __forceinline__ void async_copy16(const void* g, void* l) {
    __builtin_amdgcn_global_load_lds((const GLOBAL_AS void*)g, (LDS_AS void*)l, 16, 0, 0);
}

static __device__ __forceinline__ float gelu_tanh(float u) {
    float inner = 0.7978845608028654f * (u + 0.044715f * u * u * u);
    return 0.5f * u * (1.f + tanhf(inner));  // gelu approximate=True
}

// ---------------- fused prep: x fp32->bf16 (blocks 0..16383) +
// transpose/convert Wk/Wv -> bf16 W^T[h][k] (blocks 16384..18431) -------------
__global__ __launch_bounds__(256) void prep_kernel(
    const float4* __restrict__ x, uint4* __restrict__ xb,
    const float* __restrict__ Wk, const float* __restrict__ Wv,
    unsigned short* __restrict__ WkT, unsigned short* __restrict__ WvT)
{
    __shared__ float tile[32][33];
    int tid = threadIdx.x;
    if (blockIdx.x < 16384) {
        size_t t = (size_t)blockIdx.x * 256 + tid;  // 4M threads, 8 floats each
        float4 f0 = x[t * 2], f1 = x[t * 2 + 1];
        uint4 a;
        a.x = f2bf(f0.x) | (f2bf(f0.y) << 16);
        a.y = f2bf(f0.z) | (f2bf(f0.w) << 16);
        a.z = f2bf(f1.x) | (f2bf(f1.y) << 16);
        a.w = f2bf(f1.z) | (f2bf(f1.w) << 16);
        xb[t] = a;
    } else {
        int b2 = blockIdx.x - 16384;  // 2048 blocks: 32 h-tiles x 32 k-tiles x 2
        const float* src = (b2 >> 10) ? Wv : Wk;
        unsigned short* dst = (b2 >> 10) ? WvT : WkT;
        int h0 = (b2 & 31) * 32, k0 = ((b2 >> 5) & 31) * 32;
        int tx = tid & 31, ty = tid >> 5;  // 32 x 8
#pragma unroll
        for (int i = 0; i < 4; i++)
            tile[ty + i * 8][tx] = src[(size_t)(k0 + ty + i * 8) * DCH + h0 + tx];
        __syncthreads();
#pragma unroll
        for (int i = 0; i < 4; i++)
            dst[(size_t)(h0 + ty + i * 8) * DCH + k0 + tx] =
                (unsigned short)f2bf(tile[tx][ty + i * 8]);
    }
}

// ---------------- standalone wt (slow path only) -----------------------------
__global__ __launch_bounds__(256) void wt_kernel(
    const float* __restrict__ Wk, const float* __restrict__ Wv,
    unsigned short* __restrict__ WkT, unsigned short* __restrict__ WvT)
{
    __shared__ float tile[32][33];
    const float* src = blockIdx.z ? Wv : Wk;
    unsigned short* dst = blockIdx.z ? WvT : WkT;
    int h0 = blockIdx.x * 32, k0 = blockIdx.y * 32;
    int tx = threadIdx.x, ty = threadIdx.y;
#pragma unroll
    for (int i = 0; i < 4; i++)
        tile[ty + i * 8][tx] = src[(size_t)(k0 + ty + i * 8) * DCH + h0 + tx];
    __syncthreads();
#pragma unroll
    for (int i = 0; i < 4; i++)
        dst[(size_t)(h0 + ty + i * 8) * DCH + k0 + tx] =
            (unsigned short)f2bf(tile[tx][ty + i * 8]);
}

// ---------------- fast path: fused K/V projection + fmap + reduction ---------
// v7 = v5 pipeline + INTRA-ITER READ/MFMA INTERLEAVE. v5/v6 measured 175us
// with MfmaUtil 33% and conflicts fixed (12.6M -> 16K): the remaining cost is
// phase serialization -- B-frags were read LAST so the first MFMA's lgkmcnt
// waited for ~all 12 ds_reads, making each iter [LDS storm ~1200cy] then
// [MFMA storm ~1240cy] with no overlap (32x4x~2900 = 370-420K cyc = measured).
// Fix: read bkf/bvf FIRST, then ladder af[mt+1] ahead of the 4 MFMAs using
// af[mt] -- program order lets the compiler emit partial lgkmcnt (m97-style),
// so MFMA chases the read stream and both pipes run concurrently.
__global__ __launch_bounds__(512, 2) void kv_gemm_fast(
    const unsigned short* __restrict__ xb,
    const unsigned short* __restrict__ WkT,
    const unsigned short* __restrict__ WvT,
    const float* __restrict__ bk,
    const float* __restrict__ bv,
    float* __restrict__ part)
{
    __shared__ __align__(16) unsigned short sA[3][256 * 32];  // 48 KB
    __shared__ __align__(16) unsigned short sK[3][128 * 32];  // 24 KB
    __shared__ __align__(16) unsigned short sV[3][128 * 32];  // 24 KB

    // XCD swizzle: 1024 blocks = 8 XCD x 128; all 8 h-tiles of one
    // (n,s_tile) stay on the same XCD so the 512 KB A-panel L2-hits.
    int b = blockIdx.x;
    int r = b & 7, j = b >> 3;
    int h_tile = j & 7;                 // 8 h-tiles x 128h
    int ns = r * 16 + (j >> 3);         // 128 (n,s) pairs
    int n = ns >> 4, s_tile = ns & 15;
    int s0 = s_tile * 256, h0 = h_tile * 128;

    int tid = threadIdx.x;
    int lane = tid & 63, wid = tid >> 6;   // 8 waves
    int sg = wid >> 2, hg = wid & 3;       // 2 s-groups x 4 h-groups
    int col = lane & 15, lhi = lane >> 4;

    // A staging: 1024 chunks/tile, 2 per thread: c = i*512 + tid
    const unsigned short* gA[2];
#pragma unroll
    for (int i = 0; i < 2; i++) {
        int c = i * 512 + tid;
        int row = c >> 2, c8 = (c & 3) ^ ((row >> 1) & 3);
        gA[i] = xb + (size_t)(n * SEQ + s0 + row) * DCH + c8 * 8;
    }
    // K/V staging: 512 chunks each, 1 per thread: c = tid
    const unsigned short* gK;
    const unsigned short* gV;
    {
        int c = tid;
        int row = c >> 2, c8 = (c & 3) ^ ((row >> 1) & 3);
        gK = WkT + (size_t)(h0 + row) * DCH + c8 * 8;
        gV = WvT + (size_t)(h0 + row) * DCH + c8 * 8;
    }
    int aBase = wid * 64 * 8;  // LDS short-offset of this wave's lane-0 chunk

    f32x4 acck[8][2], accv[8][2];
#pragma unroll
    for (int mt = 0; mt < 8; mt++)
#pragma unroll
        for (int nt = 0; nt < 2; nt++) {
            acck[mt][nt] = (f32x4){0.f, 0.f, 0.f, 0.f};
            accv[mt][nt] = (f32x4){0.f, 0.f, 0.f, 0.f};
        }

    // prologue: stage tiles 0 and 1 (8 loads/thread), wait tile0 only
#pragma unroll
    for (int t0 = 0; t0 < 2; t0++) {
        int k0 = t0 * 32;
#pragma unroll
        for (int i = 0; i < 2; i++)
            async_copy16(gA[i] + k0, &sA[t0][i * 512 * 8 + aBase]);
        async_copy16(gK + k0, &sK[t0][aBase]);
        async_copy16(gV + k0, &sV[t0][aBase]);
    }
    asm volatile("s_waitcnt vmcnt(4)" ::: "memory");
    __builtin_amdgcn_sched_barrier(0);
    __builtin_amdgcn_s_barrier();
    __builtin_amdgcn_sched_barrier(0);

    int q = 0;  // buffer holding tile t
    for (int t = 0; t < 32; t++) {
        int w = q + 2 >= 3 ? q - 1 : q + 2;  // buffer for tile t+2
        if (t < 30) {
            int k0 = (t + 2) * 32;
#pragma unroll
            for (int i = 0; i < 2; i++)
                async_copy16(gA[i] + k0, &sA[w][i * 512 * 8 + aBase]);
            async_copy16(gK + k0, &sK[w][aBase]);
            async_copy16(gV + k0, &sV[w][aBase]);
        }
        // B-fragments FIRST (the first MFMA depends only on these + af[0])
        bf16x8 bkf[2], bvf[2];
#pragma unroll
        for (int nt = 0; nt < 2; nt++) {
            int rowb = hg * 32 + nt * 16 + col;
            int o = rowb * 32 + ((lhi ^ ((rowb >> 1) & 3)) * 8);
            bkf[nt] = *((const bf16x8*)&sK[q][o]);
            bvf[nt] = *((const bf16x8*)&sV[q][o]);
        }
        // A-fragment ladder: read af[mt+1] before the MFMAs consuming af[mt],
        // so each 4-MFMA cluster waits on at most one outstanding ds_read.
        const unsigned short* sAq = &sA[q][0];
        {
            int rowa0 = sg * 128 + 0 * 16 + col;
            bf16x8 a_cur = *((const bf16x8*)&sAq[rowa0 * 32 + ((lhi ^ ((rowa0 >> 1) & 3)) * 8)]);
#pragma unroll
            for (int mt = 0; mt < 8; mt++) {
                bf16x8 a_nxt = a_cur;
                if (mt < 7) {
                    int rowa = sg * 128 + (mt + 1) * 16 + col;
                    a_nxt = *((const bf16x8*)&sAq[rowa * 32 + ((lhi ^ ((rowa >> 1) & 3)) * 8)]);
                }
                __builtin_amdgcn_s_setprio(1);
                acck[mt][0] = __builtin_amdgcn_mfma_f32_16x16x32_bf16(
                    a_cur, bkf[0], acck[mt][0], 0, 0, 0);
                accv[mt][0] = __builtin_amdgcn_mfma_f32_16x16x32_bf16(
                    a_cur, bvf[0], accv[mt][0], 0, 0, 0);
                acck[mt][1] = __builtin_amdgcn_mfma_f32_16x16x32_bf16(
                    a_cur, bkf[1], acck[mt][1], 0, 0, 0);
                accv[mt][1] = __builtin_amdgcn_mfma_f32_16x16x32_bf16(
                    a_cur, bvf[1], accv[mt][1], 0, 0, 0);
                __builtin_amdgcn_s_setprio(0);
                a_cur = a_nxt;
            }
        }

        if (t < 30) {
            // t+1's 4 loads retired; t+2's 4 stay in flight across the barrier
            asm volatile("s_waitcnt vmcnt(4)" ::: "memory");
            __builtin_amdgcn_sched_barrier(0);
            __builtin_amdgcn_s_barrier();
            __builtin_amdgcn_sched_barrier(0);
        } else if (t == 30) {
            asm volatile("s_waitcnt vmcnt(0)" ::: "memory");
            __builtin_amdgcn_sched_barrier(0);
            __builtin_amdgcn_s_barrier();
            __builtin_amdgcn_sched_barrier(0);
        }
        q = q + 1 >= 3 ? 0 : q + 1;
    }

    // epilogue scratch aliased onto sA[0] (iter-31 readers touch only buf 1)
    float* redf = (float*)&sA[0][0];  // layout [sg][128][2]

    // fmap, pairwise product, reduce over the 256 s-rows of this tile
#pragma unroll
    for (int nt = 0; nt < 2; nt++) {
        int h_local = hg * 32 + nt * 16 + col;
        float bkv = bk[h0 + h_local];
        float bvv = bv[h0 + h_local];
        float pkv = 0.f, pks = 0.f;
#pragma unroll
        for (int mt = 0; mt < 8; mt++)
#pragma unroll
            for (int rr = 0; rr < 4; rr++) {
                float ck = acck[mt][nt][rr] + bkv;
                float cv = accv[mt][nt][rr] + bvv;
                float kq = ck > 0.f ? ck + 1.f : __expf(ck);  // elu+1
                pkv += kq * cv;
                pks += kq;
            }
        pkv += __shfl_xor(pkv, 16);
        pkv += __shfl_xor(pkv, 32);
        pks += __shfl_xor(pks, 16);
        pks += __shfl_xor(pks, 32);
        if (lhi == 0) {
            redf[(sg * 128 + h_local) * 2 + 0] = pkv;
            redf[(sg * 128 + h_local) * 2 + 1] = pks;
        }
    }
    __syncthreads();
    if (tid < 256) {
        int h = tid & 127, t2 = tid >> 7;
        float v = redf[h * 2 + t2] + redf[(128 + h) * 2 + t2];
        int ht = h_tile * 2 + (h >> 6);
        part[(((size_t)(n * 16 + ht) * 2 + t2) * 16 + s_tile) * 64 + (h & 63)] = v;
    }
}

// ---------------- slow fallback (fp32 staging, no xb needed) -----------------
__global__ __launch_bounds__(512) void kv_gemm_slow(
    const float* __restrict__ x,
    const unsigned short* __restrict__ WkT,
    const unsigned short* __restrict__ WvT,
    const float* __restrict__ bk,
    const float* __restrict__ bv,
    float* __restrict__ part)
{
    __shared__ unsigned short sA[128 * 64];
    __shared__ unsigned short sK[128 * 64];
    __shared__ unsigned short sV[128 * 64];
    __shared__ float red[2][128][2];

    int b = blockIdx.x;
    int r = b & 7, j = b >> 3;
    int ns = r * 32 + (j >> 3);
    int h_tile = j & 7;
    int n = ns >> 5, s_tile = ns & 31;
    int s0 = s_tile * 128, h0 = h_tile * 128;

    const float* xA = x + ((size_t)(n * SEQ + s0)) * DCH;

    int tid = threadIdx.x;
    int lane = tid & 63, wid = tid >> 6;
    int wsg = wid >> 2, wh = wid & 3;
    int col = lane & 15, lhi = lane >> 4;

    f32x4 acck[4][2], accv[4][2];
#pragma unroll
    for (int mt = 0; mt < 4; mt++)
#pragma unroll
        for (int nt = 0; nt < 2; nt++) {
            acck[mt][nt] = (f32x4){0.f, 0.f, 0.f, 0.f};
            accv[mt][nt] = (f32x4){0.f, 0.f, 0.f, 0.f};
        }

    for (int kk = 0; kk < 16; kk++) {
        int k0 = kk * 64;
#pragma unroll
        for (int i = 0; i < 2; i++) {
            int c = tid + i * 512;
            int row = c >> 3, c8 = c & 7;
            const float4* p = (const float4*)(xA + (size_t)row * DCH + k0 + c8 * 8);
            float4 f0 = p[0], f1 = p[1];
            unsigned int p0 = f2bf(f0.x) | (f2bf(f0.y) << 16);
            unsigned int p1 = f2bf(f0.z) | (f2bf(f0.w) << 16);
            unsigned int p2 = f2bf(f1.x) | (f2bf(f1.y) << 16);
            unsigned int p3 = f2bf(f1.z) | (f2bf(f1.w) << 16);
            uint4 pk = {p0, p1, p2, p3};
            int g = c8 ^ (row & 7);
            *((uint4*)&sA[row * 64 + g * 8]) = pk;
        }
#pragma unroll
        for (int i = 0; i < 2; i++) {
            int c = tid + i * 512;
            int row = c >> 3, c8 = c & 7;
            int g = c8 ^ (row & 7);
            *((uint4*)&sK[row * 64 + g * 8]) =
                *((const uint4*)(WkT + (size_t)(h0 + row) * DCH + k0 + c8 * 8));
            *((uint4*)&sV[row * 64 + g * 8]) =
                *((const uint4*)(WvT + (size_t)(h0 + row) * DCH + k0 + c8 * 8));
        }
        __syncthreads();
#pragma unroll
        for (int ks = 0; ks < 2; ks++) {
            bf16x8 af[4], bkf[2], bvf[2];
            int gg = ks * 4 + lhi;
#pragma unroll
            for (int mt = 0; mt < 4; mt++) {
                int rowa = wsg * 64 + mt * 16 + col;
                af[mt] = *((const bf16x8*)&sA[rowa * 64 + ((gg ^ (rowa & 7)) * 8)]);
            }
#pragma unroll
            for (int nt = 0; nt < 2; nt++) {
                int rowb = wh * 32 + nt * 16 + col;
                int o = rowb * 64 + ((gg ^ (rowb & 7)) * 8);
                bkf[nt] = *((const bf16x8*)&sK[o]);
                bvf[nt] = *((const bf16x8*)&sV[o]);
            }
#pragma unroll
            for (int mt = 0; mt < 4; mt++)
#pragma unroll
                for (int nt = 0; nt < 2; nt++) {
                    acck[mt][nt] = __builtin_amdgcn_mfma_f32_16x16x32_bf16(
                        af[mt], bkf[nt], acck[mt][nt], 0, 0, 0);
                    accv[mt][nt] = __builtin_amdgcn_mfma_f32_16x16x32_bf16(
                        af[mt], bvf[nt], accv[mt][nt], 0, 0, 0);
                }
        }
        __syncthreads();
    }

#pragma unroll
    for (int nt = 0; nt < 2; nt++) {
        int h_local = wh * 32 + nt * 16 + col;
        float bkv = bk[h0 + h_local];
        float bvv = bv[h0 + h_local];
        float pkv = 0.f, pks = 0.f;
#pragma unroll
        for (int mt = 0; mt < 4; mt++)
#pragma unroll
            for (int rr = 0; rr < 4; rr++) {
                float ck = acck[mt][nt][rr] + bkv;
                float cv = accv[mt][nt][rr] + bvv;
                float kq = ck > 0.f ? ck + 1.f : __expf(ck);
                pkv += kq * cv;
                pks += kq;
            }
        pkv += __shfl_xor(pkv, 16);
        pkv += __shfl_xor(pkv, 32);
        pks += __shfl_xor(pks, 16);
        pks += __shfl_xor(pks, 32);
        if (lhi == 0) {
            red[wsg][h_local][0] = pkv;
            red[wsg][h_local][1] = pks;
        }
    }
    __syncthreads();
    if (tid < 256) {
        int h = tid & 127, t = tid >> 7;
        float v = red[0][h][t] + red[1][h][t];
        int ht = h_tile * 2 + (h >> 6);
        part[(((size_t)(n * 16 + ht) * 2 + t) * 32 + s_tile) * 64 + (h & 63)] = v;
    }
}

// -------- reduce partials -> V = KV/Ksum, then k-split GEMM vs Wo ------------
// nst = number of s-tiles in the part layout (16 fast path, 32 slow path)
__global__ __launch_bounds__(256) void out_part_kernel(
    const float* __restrict__ part, const float* __restrict__ Wo,
    float* __restrict__ part2, int nst)
{
    __shared__ float skv[128], sks[128], vs[128];
    int n = blockIdx.x, kc = blockIdx.y, ob = blockIdx.z;
    int tid = threadIdx.x;
    {
        int h = tid & 127, t = tid >> 7;
        int ht = kc * 2 + (h >> 6);
        const float* base = part + (((size_t)(n * 16 + ht) * 2 + t) * nst) * 64;
        float s = 0.f;
#pragma unroll 4
        for (int st = 0; st < nst; st++) s += base[st * 64 + (h & 63)];
        if (t == 0) skv[h] = s; else sks[h] = s;
    }
    __syncthreads();
    if (tid < 128) vs[tid] = skv[tid] / sks[tid];
    __syncthreads();
    int o = ob * 256 + tid;
    float acc = 0.f;
#pragma unroll 8
    for (int k = 0; k < 128; k++)
        acc += vs[k] * Wo[(size_t)(kc * 128 + k) * DCH + o];
    part2[(size_t)(n * 8 + kc) * DCH + o] = acc;
}

// ---------------- finish (k-split sum + bias + gelu) fused with broadcast ----
__global__ __launch_bounds__(256) void bcast_kernel(
    const float4* __restrict__ part2, const float4* __restrict__ bo,
    float4* __restrict__ out)
{
    int n = blockIdx.x >> 7;
    int sc = blockIdx.x & 127;
    int tid = threadIdx.x;  // one float4 column group
    float4 a = bo[tid];
#pragma unroll
    for (int kc = 0; kc < 8; kc++) {
        float4 p = part2[(size_t)(n * 8 + kc) * 256 + tid];
        a.x += p.x; a.y += p.y; a.z += p.z; a.w += p.w;
    }
    float4 v;
    v.x = gelu_tanh(a.x);
    v.y = gelu_tanh(a.y);
    v.z = gelu_tanh(a.z);
    v.w = gelu_tanh(a.w);
    size_t base = ((size_t)(n * SEQ) + (size_t)sc * 32) * 256 + tid;
#pragma unroll 4
    for (int s = 0; s < 32; s++)
        out[base + (size_t)s * 256] = v;
}

extern "C" void kernel_launch(void* const* d_in, const int* in_sizes, int n_in,
                              void* d_out, int out_size, void* d_ws, size_t ws_size,
                              hipStream_t stream) {
    const float* x  = (const float*)d_in[0];
    // Wq (d_in[1]) / bq (d_in[2]) cancel: Q>0 in V = Q*KV/(Q*Ksum + 1e-6)
    // up to <=5e-8 relative perturbation (validated: absmax 2.4e-4).
    const float* Wk = (const float*)d_in[3];
    const float* bk = (const float*)d_in[4];
    const float* Wv = (const float*)d_in[5];
    const float* bv = (const float*)d_in[6];
    const float* Wo = (const float*)d_in[7];
    const float* bo = (const float*)d_in[8];

    const size_t XB_BYTES = (size_t)NBATCH * SEQ * DCH * 2;       // 64 MB
    // tail: WkT(2M) + WvT(2M) + part(8M) + part2(512K)
    const size_t TAIL = (4u << 20) + (8u << 20) + (1u << 19);
    bool fast = ws_size >= XB_BYTES + TAIL;

    char* ws = (char*)d_ws;
    unsigned short* xb = (unsigned short*)ws;                  // fast path only
    char* base = fast ? ws + XB_BYTES : ws;
    unsigned short* WkT = (unsigned short*)base;               // 2 MB bf16 [h][k]
    unsigned short* WvT = WkT + 1024 * 1024;                   // 2 MB
    float* part  = (float*)(base + 4 * 1024 * 1024);           // 8 MB partials
    float* part2 = part + (size_t)8 * 16 * 2 * 32 * 64;        // 512 KB

    if (fast) {
        prep_kernel<<<18432, 256, 0, stream>>>((const float4*)x, (uint4*)xb,
                                               Wk, Wv, WkT, WvT);
        kv_gemm_fast<<<1024, 512, 0, stream>>>(xb, WkT, WvT, bk, bv, part);
        out_part_kernel<<<dim3(8, 8, 4), 256, 0, stream>>>(part, Wo, part2, 16);
    } else {
        wt_kernel<<<dim3(32, 32, 2), dim3(32, 8), 0, stream>>>(Wk, Wv, WkT, WvT);
        kv_gemm_slow<<<2048, 512, 0, stream>>>(x, WkT, WvT, bk, bv, part);
        out_part_kernel<<<dim3(8, 8, 4), 256, 0, stream>>>(part, Wo, part2, 32);
    }
    bcast_kernel<<<1024, 256, 0, stream>>>((const float4*)part2, (const float4*)bo,
                                           (float4*)d_out);
}

// Round 8
// 411.293 us; speedup vs baseline: 1.0634x; 1.0380x over previous
//
#include <hip/hip_runtime.h>
#include <hip/hip_bf16.h>

typedef __attribute__((ext_vector_type(8))) short bf16x8;
typedef __attribute__((ext_vector_type(4))) float f32x4;

#define GLOBAL_AS __attribute__((address_space(1)))
#define LDS_AS __attribute__((address_space(3)))

#define DCH 1024
#define SEQ 4096
#define NBATCH 8

// RNE float -> bf16 (finite inputs)
static __device__ __forceinline__ unsigned int f2bf(float f) {
    unsigned int u = __float_as_uint(f);
    return (u + 0x7fffu + ((u >> 16) & 1u)) >> 16;
}

static __device__ __forceinline__ void async_copy16(const void* g, void* l) {
    __builtin_amdgcn_global_load_lds((const GLOBAL_AS void*)g, (LDS_AS void*)l, 16, 0, 0);
}

static __device__ __forceinline__ float gelu_tanh(float u) {
    float inner = 0.7978845608028654f * (u + 0.044715f * u * u * u);
    return 0.5f * u * (1.f + tanhf(inner));  // gelu approximate=True
}

// ---------------- fused prep: x fp32->bf16 (blocks 0..16383) +
// transpose/convert Wk/Wv -> bf16 W^T[h][k] (blocks 16384..18431) -------------
__global__ __launch_bounds__(256) void prep_kernel(
    const float4* __restrict__ x, uint4* __restrict__ xb,
    const float* __restrict__ Wk, const float* __restrict__ Wv,
    unsigned short* __restrict__ WkT, unsigned short* __restrict__ WvT)
{
    __shared__ float tile[32][33];
    int tid = threadIdx.x;
    if (blockIdx.x < 16384) {
        size_t t = (size_t)blockIdx.x * 256 + tid;  // 4M threads, 8 floats each
        float4 f0 = x[t * 2], f1 = x[t * 2 + 1];
        uint4 a;
        a.x = f2bf(f0.x) | (f2bf(f0.y) << 16);
        a.y = f2bf(f0.z) | (f2bf(f0.w) << 16);
        a.z = f2bf(f1.x) | (f2bf(f1.y) << 16);
        a.w = f2bf(f1.z) | (f2bf(f1.w) << 16);
        xb[t] = a;
    } else {
        int b2 = blockIdx.x - 16384;  // 2048 blocks: 32 h-tiles x 32 k-tiles x 2
        const float* src = (b2 >> 10) ? Wv : Wk;
        unsigned short* dst = (b2 >> 10) ? WvT : WkT;
        int h0 = (b2 & 31) * 32, k0 = ((b2 >> 5) & 31) * 32;
        int tx = tid & 31, ty = tid >> 5;  // 32 x 8
#pragma unroll
        for (int i = 0; i < 4; i++)
            tile[ty + i * 8][tx] = src[(size_t)(k0 + ty + i * 8) * DCH + h0 + tx];
        __syncthreads();
#pragma unroll
        for (int i = 0; i < 4; i++)
            dst[(size_t)(h0 + ty + i * 8) * DCH + k0 + tx] =
                (unsigned short)f2bf(tile[tx][ty + i * 8]);
    }
}

// ---------------- standalone wt (slow path only) -----------------------------
__global__ __launch_bounds__(256) void wt_kernel(
    const float* __restrict__ Wk, const float* __restrict__ Wv,
    unsigned short* __restrict__ WkT, unsigned short* __restrict__ WvT)
{
    __shared__ float tile[32][33];
    const float* src = blockIdx.z ? Wv : Wk;
    unsigned short* dst = blockIdx.z ? WvT : WkT;
    int h0 = blockIdx.x * 32, k0 = blockIdx.y * 32;
    int tx = threadIdx.x, ty = threadIdx.y;
#pragma unroll
    for (int i = 0; i < 4; i++)
        tile[ty + i * 8][tx] = src[(size_t)(k0 + ty + i * 8) * DCH + h0 + tx];
    __syncthreads();
#pragma unroll
    for (int i = 0; i < 4; i++)
        dst[(size_t)(h0 + ty + i * 8) * DCH + k0 + tx] =
            (unsigned short)f2bf(tile[tx][ty + i * 8]);
}

// ---------------- fast path: fused K/V projection + fmap + reduction ---------
// v8: counted-vmcnt 3-buffer pipeline (v5) x TWO INDEPENDENT BLOCKS PER CU.
// v5-v7 ran ONE 8-wave block/CU: every barrier locks the whole CU, so the
// per-iter drain (~600cy) is exposed -- MfmaUtil stuck at 33%. v2 (148us,
// 43%) won via ~2.4 independent blocks/CU whose compute covers each other's
// barrier drains (m114 overlap). v8 combines both: tile 256s x 64h, 4 waves
// (2sg x 2hg, per-wave 128s x 32h keeps the 12-read:32-MFMA ratio), LDS
// 72 KB = 3 x (A 16K + K 4K + V 4K) -> 2 blocks/CU. Barriers sync only 4
// waves; the co-resident block fills the bubbles. vmcnt(6) steady state
// (6 loads/thread/iter), never drained to 0 in the main loop.
__global__ __launch_bounds__(256, 2) void kv_gemm_fast(
    const unsigned short* __restrict__ xb,
    const unsigned short* __restrict__ WkT,
    const unsigned short* __restrict__ WvT,
    const float* __restrict__ bk,
    const float* __restrict__ bv,
    float* __restrict__ part)
{
    __shared__ __align__(16) unsigned short sA[3][256 * 32];  // 48 KB
    __shared__ __align__(16) unsigned short sK[3][64 * 32];   // 12 KB
    __shared__ __align__(16) unsigned short sV[3][64 * 32];   // 12 KB

    // XCD swizzle: 2048 blocks = 8 XCD x 256; all 16 h-tiles of one
    // (n,s_tile) stay on the same XCD so the 512 KB A-panel L2-hits.
    int b = blockIdx.x;
    int r = b & 7, j = b >> 3;
    int h_tile = j & 15;                // 16 h-tiles x 64h
    int ns = r * 16 + (j >> 4);         // 128 (n,s) pairs
    int n = ns >> 4, s_tile = ns & 15;
    int s0 = s_tile * 256, h0 = h_tile * 64;

    int tid = threadIdx.x;
    int lane = tid & 63, wid = tid >> 6;   // 4 waves
    int sg = wid >> 1, hg = wid & 1;       // 2 s-groups x 2 h-groups
    int col = lane & 15, lhi = lane >> 4;

    // A staging: 1024 chunks/tile, 4 per thread: c = i*256 + tid
    const unsigned short* gA[4];
#pragma unroll
    for (int i = 0; i < 4; i++) {
        int c = i * 256 + tid;
        int row = c >> 2, c8 = (c & 3) ^ ((row >> 1) & 3);
        gA[i] = xb + (size_t)(n * SEQ + s0 + row) * DCH + c8 * 8;
    }
    // K/V staging: 256 chunks each, 1 per thread: c = tid
    const unsigned short* gK;
    const unsigned short* gV;
    {
        int c = tid;
        int row = c >> 2, c8 = (c & 3) ^ ((row >> 1) & 3);
        gK = WkT + (size_t)(h0 + row) * DCH + c8 * 8;
        gV = WvT + (size_t)(h0 + row) * DCH + c8 * 8;
    }
    int aBase = wid * 512;  // short-offset of this wave's lane-0 chunk

    f32x4 acck[8][2], accv[8][2];
#pragma unroll
    for (int mt = 0; mt < 8; mt++)
#pragma unroll
        for (int nt = 0; nt < 2; nt++) {
            acck[mt][nt] = (f32x4){0.f, 0.f, 0.f, 0.f};
            accv[mt][nt] = (f32x4){0.f, 0.f, 0.f, 0.f};
        }

    // prologue: stage tiles 0 and 1 (12 loads/thread), wait tile0 only
#pragma unroll
    for (int t0 = 0; t0 < 2; t0++) {
        int k0 = t0 * 32;
#pragma unroll
        for (int i = 0; i < 4; i++)
            async_copy16(gA[i] + k0, &sA[t0][i * 2048 + aBase]);
        async_copy16(gK + k0, &sK[t0][aBase]);
        async_copy16(gV + k0, &sV[t0][aBase]);
    }
    asm volatile("s_waitcnt vmcnt(6)" ::: "memory");
    __builtin_amdgcn_sched_barrier(0);
    __builtin_amdgcn_s_barrier();
    __builtin_amdgcn_sched_barrier(0);

    int q = 0;  // buffer holding tile t
    for (int t = 0; t < 32; t++) {
        int w = q + 2 >= 3 ? q - 1 : q + 2;  // buffer for tile t+2
        if (t < 30) {
            int k0 = (t + 2) * 32;
#pragma unroll
            for (int i = 0; i < 4; i++)
                async_copy16(gA[i] + k0, &sA[w][i * 2048 + aBase]);
            async_copy16(gK + k0, &sK[w][aBase]);
            async_copy16(gV + k0, &sV[w][aBase]);
        }
        // fragment reads from buf q (compiler inserts lgkmcnt before MFMA)
        bf16x8 bkf[2], bvf[2];
#pragma unroll
        for (int nt = 0; nt < 2; nt++) {
            int rowb = hg * 32 + nt * 16 + col;
            int o = rowb * 32 + ((lhi ^ ((rowb >> 1) & 3)) * 8);
            bkf[nt] = *((const bf16x8*)&sK[q][o]);
            bvf[nt] = *((const bf16x8*)&sV[q][o]);
        }
        bf16x8 af[8];
#pragma unroll
        for (int mt = 0; mt < 8; mt++) {
            int rowa = sg * 128 + mt * 16 + col;
            af[mt] = *((const bf16x8*)&sA[q][rowa * 32 + ((lhi ^ ((rowa >> 1) & 3)) * 8)]);
        }
        __builtin_amdgcn_s_setprio(1);
#pragma unroll
        for (int mt = 0; mt < 8; mt++)
#pragma unroll
            for (int nt = 0; nt < 2; nt++) {
                acck[mt][nt] = __builtin_amdgcn_mfma_f32_16x16x32_bf16(
                    af[mt], bkf[nt], acck[mt][nt], 0, 0, 0);
                accv[mt][nt] = __builtin_amdgcn_mfma_f32_16x16x32_bf16(
                    af[mt], bvf[nt], accv[mt][nt], 0, 0, 0);
            }
        __builtin_amdgcn_s_setprio(0);

        if (t < 30) {
            // t+1's 6 loads retired; t+2's 6 stay in flight across the barrier
            asm volatile("s_waitcnt vmcnt(6)" ::: "memory");
            __builtin_amdgcn_sched_barrier(0);
            __builtin_amdgcn_s_barrier();
            __builtin_amdgcn_sched_barrier(0);
        } else if (t == 30) {
            asm volatile("s_waitcnt vmcnt(0)" ::: "memory");
            __builtin_amdgcn_sched_barrier(0);
            __builtin_amdgcn_s_barrier();
            __builtin_amdgcn_sched_barrier(0);
        }
        q = q + 1 >= 3 ? 0 : q + 1;
    }

    // epilogue scratch aliased onto sA[0] (iter-31 readers touch only buf 1)
    float* redf = (float*)&sA[0][0];  // layout [sg][64][2]

    // fmap, pairwise product, reduce over the 256 s-rows of this tile
#pragma unroll
    for (int nt = 0; nt < 2; nt++) {
        int h_local = hg * 32 + nt * 16 + col;
        float bkv = bk[h0 + h_local];
        float bvv = bv[h0 + h_local];
        float pkv = 0.f, pks = 0.f;
#pragma unroll
        for (int mt = 0; mt < 8; mt++)
#pragma unroll
            for (int rr = 0; rr < 4; rr++) {
                float ck = acck[mt][nt][rr] + bkv;
                float cv = accv[mt][nt][rr] + bvv;
                float kq = ck > 0.f ? ck + 1.f : __expf(ck);  // elu+1
                pkv += kq * cv;
                pks += kq;
            }
        pkv += __shfl_xor(pkv, 16);
        pkv += __shfl_xor(pkv, 32);
        pks += __shfl_xor(pks, 16);
        pks += __shfl_xor(pks, 32);
        if (lhi == 0) {
            redf[(sg * 64 + h_local) * 2 + 0] = pkv;
            redf[(sg * 64 + h_local) * 2 + 1] = pks;
        }
    }
    __syncthreads();
    if (tid < 128) {
        int h = tid & 63, t2 = tid >> 6;
        float v = redf[h * 2 + t2] + redf[(64 + h) * 2 + t2];
        part[(((size_t)(n * 16 + h_tile) * 2 + t2) * 16 + s_tile) * 64 + h] = v;
    }
}

// ---------------- slow fallback (fp32 staging, no xb needed) -----------------
__global__ __launch_bounds__(512) void kv_gemm_slow(
    const float* __restrict__ x,
    const unsigned short* __restrict__ WkT,
    const unsigned short* __restrict__ WvT,
    const float* __restrict__ bk,
    const float* __restrict__ bv,
    float* __restrict__ part)
{
    __shared__ unsigned short sA[128 * 64];
    __shared__ unsigned short sK[128 * 64];
    __shared__ unsigned short sV[128 * 64];
    __shared__ float red[2][128][2];

    int b = blockIdx.x;
    int r = b & 7, j = b >> 3;
    int ns = r * 32 + (j >> 3);
    int h_tile = j & 7;
    int n = ns >> 5, s_tile = ns & 31;
    int s0 = s_tile * 128, h0 = h_tile * 128;

    const float* xA = x + ((size_t)(n * SEQ + s0)) * DCH;

    int tid = threadIdx.x;
    int lane = tid & 63, wid = tid >> 6;
    int wsg = wid >> 2, wh = wid & 3;
    int col = lane & 15, lhi = lane >> 4;

    f32x4 acck[4][2], accv[4][2];
#pragma unroll
    for (int mt = 0; mt < 4; mt++)
#pragma unroll
        for (int nt = 0; nt < 2; nt++) {
            acck[mt][nt] = (f32x4){0.f, 0.f, 0.f, 0.f};
            accv[mt][nt] = (f32x4){0.f, 0.f, 0.f, 0.f};
        }

    for (int kk = 0; kk < 16; kk++) {
        int k0 = kk * 64;
#pragma unroll
        for (int i = 0; i < 2; i++) {
            int c = tid + i * 512;
            int row = c >> 3, c8 = c & 7;
            const float4* p = (const float4*)(xA + (size_t)row * DCH + k0 + c8 * 8);
            float4 f0 = p[0], f1 = p[1];
            unsigned int p0 = f2bf(f0.x) | (f2bf(f0.y) << 16);
            unsigned int p1 = f2bf(f0.z) | (f2bf(f0.w) << 16);
            unsigned int p2 = f2bf(f1.x) | (f2bf(f1.y) << 16);
            unsigned int p3 = f2bf(f1.z) | (f2bf(f1.w) << 16);
            uint4 pk = {p0, p1, p2, p3};
            int g = c8 ^ (row & 7);
            *((uint4*)&sA[row * 64 + g * 8]) = pk;
        }
#pragma unroll
        for (int i = 0; i < 2; i++) {
            int c = tid + i * 512;
            int row = c >> 3, c8 = c & 7;
            int g = c8 ^ (row & 7);
            *((uint4*)&sK[row * 64 + g * 8]) =
                *((const uint4*)(WkT + (size_t)(h0 + row) * DCH + k0 + c8 * 8));
            *((uint4*)&sV[row * 64 + g * 8]) =
                *((const uint4*)(WvT + (size_t)(h0 + row) * DCH + k0 + c8 * 8));
        }
        __syncthreads();
#pragma unroll
        for (int ks = 0; ks < 2; ks++) {
            bf16x8 af[4], bkf[2], bvf[2];
            int gg = ks * 4 + lhi;
#pragma unroll
            for (int mt = 0; mt < 4; mt++) {
                int rowa = wsg * 64 + mt * 16 + col;
                af[mt] = *((const bf16x8*)&sA[rowa * 64 + ((gg ^ (rowa & 7)) * 8)]);
            }
#pragma unroll
            for (int nt = 0; nt < 2; nt++) {
                int rowb = wh * 32 + nt * 16 + col;
                int o = rowb * 64 + ((gg ^ (rowb & 7)) * 8);
                bkf[nt] = *((const bf16x8*)&sK[o]);
                bvf[nt] = *((const bf16x8*)&sV[o]);
            }
#pragma unroll
            for (int mt = 0; mt < 4; mt++)
#pragma unroll
                for (int nt = 0; nt < 2; nt++) {
                    acck[mt][nt] = __builtin_amdgcn_mfma_f32_16x16x32_bf16(
                        af[mt], bkf[nt], acck[mt][nt], 0, 0, 0);
                    accv[mt][nt] = __builtin_amdgcn_mfma_f32_16x16x32_bf16(
                        af[mt], bvf[nt], accv[mt][nt], 0, 0, 0);
                }
        }
        __syncthreads();
    }

#pragma unroll
    for (int nt = 0; nt < 2; nt++) {
        int h_local = wh * 32 + nt * 16 + col;
        float bkv = bk[h0 + h_local];
        float bvv = bv[h0 + h_local];
        float pkv = 0.f, pks = 0.f;
#pragma unroll
        for (int mt = 0; mt < 4; mt++)
#pragma unroll
            for (int rr = 0; rr < 4; rr++) {
                float ck = acck[mt][nt][rr] + bkv;
                float cv = accv[mt][nt][rr] + bvv;
                float kq = ck > 0.f ? ck + 1.f : __expf(ck);
                pkv += kq * cv;
                pks += kq;
            }
        pkv += __shfl_xor(pkv, 16);
        pkv += __shfl_xor(pkv, 32);
        pks += __shfl_xor(pks, 16);
        pks += __shfl_xor(pks, 32);
        if (lhi == 0) {
            red[wsg][h_local][0] = pkv;
            red[wsg][h_local][1] = pks;
        }
    }
    __syncthreads();
    if (tid < 256) {
        int h = tid & 127, t = tid >> 7;
        float v = red[0][h][t] + red[1][h][t];
        int ht = h_tile * 2 + (h >> 6);
        part[(((size_t)(n * 16 + ht) * 2 + t) * 32 + s_tile) * 64 + (h & 63)] = v;
    }
}

// -------- reduce partials -> V = KV/Ksum, then k-split GEMM vs Wo ------------
// nst = number of s-tiles in the part layout (16 fast path, 32 slow path)
__global__ __launch_bounds__(256) void out_part_kernel(
    const float* __restrict__ part, const float* __restrict__ Wo,
    float* __restrict__ part2, int nst)
{
    __shared__ float skv[128], sks[128], vs[128];
    int n = blockIdx.x, kc = blockIdx.y, ob = blockIdx.z;
    int tid = threadIdx.x;
    {
        int h = tid & 127, t = tid >> 7;
        int ht = kc * 2 + (h >> 6);
        const float* base = part + (((size_t)(n * 16 + ht) * 2 + t) * nst) * 64;
        float s = 0.f;
#pragma unroll 4
        for (int st = 0; st < nst; st++) s += base[st * 64 + (h & 63)];
        if (t == 0) skv[h] = s; else sks[h] = s;
    }
    __syncthreads();
    if (tid < 128) vs[tid] = skv[tid] / sks[tid];
    __syncthreads();
    int o = ob * 256 + tid;
    float acc = 0.f;
#pragma unroll 8
    for (int k = 0; k < 128; k++)
        acc += vs[k] * Wo[(size_t)(kc * 128 + k) * DCH + o];
    part2[(size_t)(n * 8 + kc) * DCH + o] = acc;
}

// ---------------- finish (k-split sum + bias + gelu) fused with broadcast ----
__global__ __launch_bounds__(256) void bcast_kernel(
    const float4* __restrict__ part2, const float4* __restrict__ bo,
    float4* __restrict__ out)
{
    int n = blockIdx.x >> 7;
    int sc = blockIdx.x & 127;
    int tid = threadIdx.x;  // one float4 column group
    float4 a = bo[tid];
#pragma unroll
    for (int kc = 0; kc < 8; kc++) {
        float4 p = part2[(size_t)(n * 8 + kc) * 256 + tid];
        a.x += p.x; a.y += p.y; a.z += p.z; a.w += p.w;
    }
    float4 v;
    v.x = gelu_tanh(a.x);
    v.y = gelu_tanh(a.y);
    v.z = gelu_tanh(a.z);
    v.w = gelu_tanh(a.w);
    size_t base = ((size_t)(n * SEQ) + (size_t)sc * 32) * 256 + tid;
#pragma unroll 4
    for (int s = 0; s < 32; s++)
        out[base + (size_t)s * 256] = v;
}

extern "C" void kernel_launch(void* const* d_in, const int* in_sizes, int n_in,
                              void* d_out, int out_size, void* d_ws, size_t ws_size,
                              hipStream_t stream) {
    const float* x  = (const float*)d_in[0];
    // Wq (d_in[1]) / bq (d_in[2]) cancel: Q>0 in V = Q*KV/(Q*Ksum + 1e-6)
    // up to <=5e-8 relative perturbation (validated: absmax 2.4e-4).
    const float* Wk = (const float*)d_in[3];
    const float* bk = (const float*)d_in[4];
    const float* Wv = (const float*)d_in[5];
    const float* bv = (const float*)d_in[6];
    const float* Wo = (const float*)d_in[7];
    const float* bo = (const float*)d_in[8];

    const size_t XB_BYTES = (size_t)NBATCH * SEQ * DCH * 2;       // 64 MB
    // tail: WkT(2M) + WvT(2M) + part(8M) + part2(512K)
    const size_t TAIL = (4u << 20) + (8u << 20) + (1u << 19);
    bool fast = ws_size >= XB_BYTES + TAIL;

    char* ws = (char*)d_ws;
    unsigned short* xb = (unsigned short*)ws;                  // fast path only
    char* base = fast ? ws + XB_BYTES : ws;
    unsigned short* WkT = (unsigned short*)base;               // 2 MB bf16 [h][k]
    unsigned short* WvT = WkT + 1024 * 1024;                   // 2 MB
    float* part  = (float*)(base + 4 * 1024 * 1024);           // 8 MB partials
    float* part2 = part + (size_t)8 * 16 * 2 * 32 * 64;        // 512 KB

    if (fast) {
        prep_kernel<<<18432, 256, 0, stream>>>((const float4*)x, (uint4*)xb,
                                               Wk, Wv, WkT, WvT);
        kv_gemm_fast<<<2048, 256, 0, stream>>>(xb, WkT, WvT, bk, bv, part);
        out_part_kernel<<<dim3(8, 8, 4), 256, 0, stream>>>(part, Wo, part2, 16);
    } else {
        wt_kernel<<<dim3(32, 32, 2), dim3(32, 8), 0, stream>>>(Wk, Wv, WkT, WvT);
        kv_gemm_slow<<<2048, 512, 0, stream>>>(x, WkT, WvT, bk, bv, part);
        out_part_kernel<<<dim3(8, 8, 4), 256, 0, stream>>>(part, Wo, part2, 32);
    }
    bcast_kernel<<<1024, 256, 0, stream>>>((const float4*)part2, (const float4*)bo,
                                           (float4*)d_out);
}